// Round 6
// baseline (335.591 us; speedup 1.0000x reference)
//
#include <hip/hip_runtime.h>

#define N_NODES 50000
#define IN_CH 128
#define HID 128
#define OUT_CH 40
#define N_LAYERS 3
#define N_EDGES 600000
#define DSTRIDE 64    // fixed col slots/node; P(Poisson(12) > 64) ~ 1e-30
#define DEGSTRIDE 16  // 64B per counter

typedef __attribute__((ext_vector_type(8))) short short8;
typedef __attribute__((ext_vector_type(4))) float floatx4;

static __device__ __forceinline__ unsigned short f32_to_bf16(float f) {
  unsigned u = __float_as_uint(f);
  unsigned r = 0x7FFFu + ((u >> 16) & 1u);  // RNE
  return (unsigned short)((u + r) >> 16);
}
static __device__ __forceinline__ float bf16_to_f32(unsigned short h) {
  return __uint_as_float(((unsigned)h) << 16);
}

// ---- tiny deg-zero kernel (must complete before prep_csr's csr blocks) ----
#define ZERO_BLOCKS 782  // ceil(50000*16/4/256)
__global__ __launch_bounds__(256) void zero_deg_kernel(int* __restrict__ deg) {
  int i = (blockIdx.x * 256 + threadIdx.x) * 4;
  if (i < N_NODES * DEGSTRIDE) *(int4*)(deg + i) = make_int4(0, 0, 0, 0);
}

#define CSRB 586          // ceil((600000/4)/256) — csr blocks, FIRST in grid
#define CONV_BLOCKS 6250  // (N*128/4)/256
#define W_BLOCKS 408      // (6*16384 + 48*128)/256

// == combined prep + CSR: csr blocks overlap with streaming prep blocks =====
// csr is atomic-latency-bound (11% HBM, 0.4% VALU standalone); prep is pure
// streaming BW. One grid runs both concurrently: csr blocks dispatched first
// so their ~42us atomic wall hides under prep's 38MB of streaming traffic.
// Measured R5: 45.2us combined ~= csr alone; prep fully hidden.
__global__ __launch_bounds__(256) void prep_csr_kernel(
    const float* __restrict__ x, const float* __restrict__ W1,
    const float* __restrict__ W2, const float* __restrict__ Wc,
    const int* __restrict__ ei, unsigned short* __restrict__ xb,
    unsigned short* __restrict__ WT, unsigned short* __restrict__ WcT,
    unsigned short* __restrict__ hb1, int* __restrict__ deg,
    int* __restrict__ col) {
  const int b = blockIdx.x;
  const int t = threadIdx.x;
  if (b < CSRB) {
    // ---- CSR: 4 edges/thread (atomic ILP), fixed-stride slot fill ----
    int base = (b * 256 + t) * 4;
    if (base < N_EDGES) {
      int4 s4 = *(const int4*)(ei + base);
      int4 d4 = *(const int4*)(ei + N_EDGES + base);
      int p0 = atomicAdd(&deg[(size_t)d4.x * DEGSTRIDE], 1);
      int p1 = atomicAdd(&deg[(size_t)d4.y * DEGSTRIDE], 1);
      int p2 = atomicAdd(&deg[(size_t)d4.z * DEGSTRIDE], 1);
      int p3 = atomicAdd(&deg[(size_t)d4.w * DEGSTRIDE], 1);
      col[(size_t)d4.x * DSTRIDE + p0] = s4.x;
      col[(size_t)d4.y * DSTRIDE + p1] = s4.y;
      col[(size_t)d4.z * DSTRIDE + p2] = s4.z;
      col[(size_t)d4.w * DSTRIDE + p3] = s4.w;
    }
  } else if (b < CSRB + CONV_BLOCKS) {
    int i = ((b - CSRB) * 256 + t) * 4;
    if (i < N_NODES * 128) {
      float4 v = *(const float4*)(x + i);
      ushort4 o;
      o.x = f32_to_bf16(v.x); o.y = f32_to_bf16(v.y);
      o.z = f32_to_bf16(v.z); o.w = f32_to_bf16(v.w);
      *(ushort4*)(xb + i) = o;
    }
  } else if (b < CSRB + CONV_BLOCKS + W_BLOCKS) {
    int o = (b - CSRB - CONV_BLOCKS) * 256 + t;
    if (o < 6 * 16384) {
      int mat = o >> 14;
      int r = o & 16383;
      int n = r >> 7;
      int k = r & 127;
      const float* W = (mat < 3) ? (W1 + (size_t)mat * 16384)
                                 : (W2 + (size_t)(mat - 3) * 16384);
      WT[(size_t)mat * 16384 + (size_t)n * 128 + k] =
          f32_to_bf16(W[(size_t)k * 128 + n]);
    } else if (o < 6 * 16384 + 48 * 128) {
      int r = o - 6 * 16384;
      int n = r >> 7;
      int k = r & 127;
      float v = (n < OUT_CH) ? Wc[(size_t)k * OUT_CH + n] : 0.0f;
      WcT[(size_t)n * 128 + k] = f32_to_bf16(v);
    }
  } else {
    // zero phantom rows (index N_NODES) of the two gather sources
    if (t < 128) xb[(size_t)N_NODES * 128 + t] = 0;
    else hb1[(size_t)N_NODES * 128 + (t - 128)] = 0;
  }
}

// ================= Aggregation (bf16): z = h[n] + sum_nbrs ==================
// v2: TWO rows per gather instruction. Lane reads ushort4 (8B); lanes 0-31
// cover row A, lanes 32-63 cover row B -> 512B/instruction, half the issue
// slots / waitcnt depth of the 1-row (4B/lane) version, same bytes + VALU.
// Discriminates issue-bound vs fabric-bound: if flat, aggregate is at the
// ~3.5 TB/s L2-miss fabric ceiling (8 XCD x 12.8MB table duplication).
// deg/col wave-uniform via readfirstlane; tail slots clamp to the phantom
// zero row. Final shfl_xor(32) folds the two halves; half 0 stores.
__global__ __launch_bounds__(256) void aggregate_kernel(
    const unsigned short* __restrict__ h, const int* __restrict__ deg,
    const int* __restrict__ col, unsigned short* __restrict__ z) {
  int n = __builtin_amdgcn_readfirstlane(blockIdx.x * 4 + (threadIdx.x >> 6));
  const int q = threadIdx.x & 63;
  const int half = q >> 5;       // which of the 2 rows this lane covers
  const int c4 = (q & 31) * 4;   // channel base (4 channels/lane)
  ushort4 sv = *(const ushort4*)(h + (size_t)n * 128 + c4);
  float acc0[4], acc1[4];
  acc0[0] = (half == 0) ? bf16_to_f32(sv.x) : 0.f;
  acc0[1] = (half == 0) ? bf16_to_f32(sv.y) : 0.f;
  acc0[2] = (half == 0) ? bf16_to_f32(sv.z) : 0.f;
  acc0[3] = (half == 0) ? bf16_to_f32(sv.w) : 0.f;
#pragma unroll
  for (int j = 0; j < 4; ++j) acc1[j] = 0.f;

  int dg = __builtin_amdgcn_readfirstlane(deg[(size_t)n * DEGSTRIDE]);
  int cnt = (dg + 15) & ~15;
  const int* cp = col + (size_t)n * DSTRIDE;
  for (int i = 0; i < cnt; i += 16) {
    int ss[16];
#pragma unroll
    for (int k = 0; k < 16; ++k) {
      int sl = cp[i + k];  // in-bounds; garbage beyond dg is clamped below
      ss[k] = __builtin_amdgcn_readfirstlane((i + k < dg) ? sl : N_NODES);
    }
    ushort4 vv[8];
#pragma unroll
    for (int k = 0; k < 8; ++k) {
      int myrow = half ? ss[2 * k + 1] : ss[2 * k];
      vv[k] = *(const ushort4*)(h + (size_t)myrow * 128 + c4);
    }
#pragma unroll
    for (int k = 0; k < 8; ++k) {
      float* a = (k & 1) ? acc1 : acc0;
      a[0] += bf16_to_f32(vv[k].x);
      a[1] += bf16_to_f32(vv[k].y);
      a[2] += bf16_to_f32(vv[k].z);
      a[3] += bf16_to_f32(vv[k].w);
    }
  }
  ushort4 o;
#pragma unroll
  for (int j = 0; j < 4; ++j) {
    float s = acc0[j] + acc1[j];
    s += __shfl_xor(s, 32, 64);  // fold row-halves (same channels at q^32)
    ((unsigned short*)&o)[j] = f32_to_bf16(s);
  }
  if (half == 0) *(ushort4*)(z + (size_t)n * 128 + c4) = o;
}

// ============ Fused layer MLP: Z = relu(relu(A@W1+b1)@W2+b2) ===============
// LDS-staged weights + 16 rows/wave. 64 rows/block, 4 waves (grid 782 =
// 3128 waves = 3 waves/SIMD). W staged into LDS once per GEMM (32KB, L2-hot
// source); B-frags become ds_read_b128. LDS = 34.8K (Wl) + 17.4K (T) = 52.2K
// -> 3 blocks/CU. Intermediate T rows wave-private; barriers only around Wl
// restage. LAST=true fuses the classifier (WcT direct-global; out f32).
// Frag layouts (measured m89/m91): A/B [idx=lane&15][k=(lane>>4)*8+j];
// C/D row=(lane>>4)*4+reg, col=lane&15.
template <bool LAST>
__global__ __launch_bounds__(256) void layer_pair_kernel(
    const unsigned short* __restrict__ A, const unsigned short* __restrict__ WT1,
    const float* __restrict__ b1, const unsigned short* __restrict__ WT2,
    const float* __restrict__ b2, unsigned short* __restrict__ Z,
    const unsigned short* __restrict__ WcT, const float* __restrict__ bc,
    float* __restrict__ out, int M) {
  __shared__ __align__(16) unsigned short Wl[128][136];  // staged weight
  __shared__ __align__(16) unsigned short T[64][136];    // activations
  const int tid = threadIdx.x;
  const int w = tid >> 6;
  const int lane = tid & 63;
  const int qg = lane >> 4;
  const int ln = lane & 15;
  const int row0 = blockIdx.x * 64;
  const int rbase = w * 16;
  const int r0 = row0 + rbase + ln;
  const short8 zero8 = {0, 0, 0, 0, 0, 0, 0, 0};

  // ---- stage WT1 -> Wl (2048 chunks of 8 bf16 over 256 threads) ----
#pragma unroll
  for (int j = 0; j < 8; ++j) {
    int slot = tid + j * 256;
    int row = slot >> 4;
    int kb = slot & 15;
    *(short8*)&Wl[row][kb * 8] = *(const short8*)(WT1 + (size_t)row * 128 + kb * 8);
  }
  __syncthreads();

  // ---- GEMM1: A direct-global, B from LDS ----
  floatx4 acc[8];
#pragma unroll
  for (int ct = 0; ct < 8; ++ct) acc[ct] = (floatx4){0.f, 0.f, 0.f, 0.f};
#pragma unroll
  for (int ks = 0; ks < 4; ++ks) {
    const int koff = ks * 32 + qg * 8;
    short8 a = (r0 < M) ? *(const short8*)(A + (size_t)r0 * 128 + koff) : zero8;
#pragma unroll
    for (int ct = 0; ct < 8; ++ct) {
      short8 b = *(const short8*)&Wl[ct * 16 + ln][koff];
      acc[ct] = __builtin_amdgcn_mfma_f32_16x16x32_bf16(a, b, acc[ct], 0, 0, 0);
    }
  }
  // ---- epilogue1 -> wave-private T rows (bias+relu+bf16) ----
#pragma unroll
  for (int ct = 0; ct < 8; ++ct) {
    float bv = b1[ct * 16 + ln];
#pragma unroll
    for (int r = 0; r < 4; ++r) {
      float v = fmaxf(acc[ct][r] + bv, 0.0f);
      T[rbase + qg * 4 + r][ct * 16 + ln] = f32_to_bf16(v);
    }
  }

  // ---- restage Wl with WT2 (all waves must be done with WT1) ----
  __syncthreads();
#pragma unroll
  for (int j = 0; j < 8; ++j) {
    int slot = tid + j * 256;
    int row = slot >> 4;
    int kb = slot & 15;
    *(short8*)&Wl[row][kb * 8] = *(const short8*)(WT2 + (size_t)row * 128 + kb * 8);
  }
  __syncthreads();

  // ---- GEMM2: A from own T rows, B from LDS ----
  floatx4 acc2[8];
#pragma unroll
  for (int ct = 0; ct < 8; ++ct) acc2[ct] = (floatx4){0.f, 0.f, 0.f, 0.f};
#pragma unroll
  for (int ks = 0; ks < 4; ++ks) {
    const int koff = ks * 32 + qg * 8;
    short8 a = *(const short8*)&T[rbase + ln][koff];
#pragma unroll
    for (int ct = 0; ct < 8; ++ct) {
      short8 b = *(const short8*)&Wl[ct * 16 + ln][koff];
      acc2[ct] = __builtin_amdgcn_mfma_f32_16x16x32_bf16(a, b, acc2[ct], 0, 0, 0);
    }
  }
  // ---- epilogue2 -> own T rows ----
#pragma unroll
  for (int ct = 0; ct < 8; ++ct) {
    float bv = b2[ct * 16 + ln];
#pragma unroll
    for (int r = 0; r < 4; ++r) {
      float v = fmaxf(acc2[ct][r] + bv, 0.0f);
      T[rbase + qg * 4 + r][ct * 16 + ln] = f32_to_bf16(v);
    }
  }

  if (LAST) {
    // ---- GEMM3 (classifier): A from own T rows, B = WcT direct-global ----
    floatx4 acc3[3];
#pragma unroll
    for (int ct = 0; ct < 3; ++ct) acc3[ct] = (floatx4){0.f, 0.f, 0.f, 0.f};
#pragma unroll
    for (int ks = 0; ks < 4; ++ks) {
      const int koff = ks * 32 + qg * 8;
      short8 a = *(const short8*)&T[rbase + ln][koff];
#pragma unroll
      for (int ct = 0; ct < 3; ++ct) {
        short8 b = *(const short8*)(WcT + (size_t)(ct * 16 + ln) * 128 + koff);
        acc3[ct] = __builtin_amdgcn_mfma_f32_16x16x32_bf16(a, b, acc3[ct], 0, 0, 0);
      }
    }
#pragma unroll
    for (int ct = 0; ct < 3; ++ct) {
      int colg = ct * 16 + ln;
      if (colg < OUT_CH) {
        float bv = bc[colg];
#pragma unroll
        for (int r = 0; r < 4; ++r) {
          int row = row0 + rbase + qg * 4 + r;
          if (row < M) out[(size_t)row * OUT_CH + colg] = acc3[ct][r] + bv;
        }
      }
    }
  } else {
    __syncthreads();
    // ---- cooperative coalesced store: 64 rows x 256B ----
#pragma unroll
    for (int j = 0; j < 4; ++j) {
      int slot = tid + j * 256;  // 0..1023 chunks of 8 bf16
      int row = slot >> 4;
      int kb = slot & 15;
      if (row0 + row < M) {
        short8 v = *(const short8*)&T[row][kb * 8];
        *(short8*)(Z + (size_t)(row0 + row) * 128 + kb * 8) = v;
      }
    }
  }
}

// ---------------------------------------------------------------------------
extern "C" void kernel_launch(void* const* d_in, const int* in_sizes, int n_in,
                              void* d_out, int out_size, void* d_ws,
                              size_t ws_size, hipStream_t stream) {
  const float* x = (const float*)d_in[0];
  const int* ei = (const int*)d_in[2];  // int32 [2, E]
  const float* W1 = (const float*)d_in[3];
  const float* b1 = (const float*)d_in[4];
  const float* W2 = (const float*)d_in[5];
  const float* b2 = (const float*)d_in[6];
  const float* Wc = (const float*)d_in[7];
  const float* bc = (const float*)d_in[8];
  float* out = (float*)d_out;

  // Node buffers have N+1 rows: row N_NODES is the phantom zero row.
  const size_t NF = (size_t)(N_NODES + 1) * 128;
  unsigned short* hb0 = (unsigned short*)d_ws;
  unsigned short* hb1 = hb0 + NF;
  unsigned short* xbf = hb1 + NF;
  unsigned short* WT = xbf + NF;         // 6*16384 bf16
  unsigned short* WcT = WT + 6 * 16384;  // 48*128 bf16
  int* deg = (int*)(WcT + 48 * 128);     // [N * DEGSTRIDE] (64B-padded ctrs)
  int* col = deg + (size_t)N_NODES * DEGSTRIDE;  // [N * DSTRIDE]

  const dim3 blk(256);
  const int aggr_grid = N_NODES / 4;          // 12500
  const int pair_grid = (N_NODES + 63) / 64;  // 782

  // ---- deg = 0 (tiny; must complete before prep_csr's csr blocks) ----
  zero_deg_kernel<<<ZERO_BLOCKS, blk, 0, stream>>>(deg);

  // ---- combined prep + CSR: csr atomic wall overlaps streaming prep ----
  prep_csr_kernel<<<CSRB + CONV_BLOCKS + W_BLOCKS + 1, blk, 0, stream>>>(
      x, W1, W2, Wc, ei, xbf, WT, WcT, hb1, deg, col);

  // ---- 3 GIN layers; classifier fused into the last pair ----
  // Fixed buffers: agg h->hb0; pair hb0->hb1; next h = hb1 (old h dead).
  const unsigned short* h = xbf;
  for (int l = 0; l < N_LAYERS; ++l) {
    aggregate_kernel<<<aggr_grid, blk, 0, stream>>>(h, deg, col, hb0);
    if (l < N_LAYERS - 1) {
      layer_pair_kernel<false><<<pair_grid, blk, 0, stream>>>(
          hb0, WT + (size_t)l * 16384, b1 + (size_t)l * 128,
          WT + (size_t)(3 + l) * 16384, b2 + (size_t)l * 128, hb1,
          nullptr, nullptr, nullptr, N_NODES);
      h = hb1;
    } else {
      layer_pair_kernel<true><<<pair_grid, blk, 0, stream>>>(
          hb0, WT + (size_t)l * 16384, b1 + (size_t)l * 128,
          WT + (size_t)(3 + l) * 16384, b2 + (size_t)l * 128, nullptr,
          WcT, bc, out, N_NODES);
    }
  }
}

// Round 7
// 237.938 us; speedup vs baseline: 1.4104x; 1.4104x over previous
//
#include <hip/hip_runtime.h>

#define N_NODES 50000
#define IN_CH 128
#define HID 128
#define OUT_CH 40
#define N_LAYERS 3
#define N_EDGES 600000
#define DSTRIDE 64    // fixed col slots/node; P(Poisson(12) > 64) ~ 1e-30
#define DEGSTRIDE 16  // 64B per counter
#define NXCD 8
#define CHUNK 6250    // nodes per XCD class (N/8)

typedef __attribute__((ext_vector_type(8))) short short8;
typedef __attribute__((ext_vector_type(4))) float floatx4;

static __device__ __forceinline__ unsigned short f32_to_bf16(float f) {
  unsigned u = __float_as_uint(f);
  unsigned r = 0x7FFFu + ((u >> 16) & 1u);  // RNE
  return (unsigned short)((u + r) >> 16);
}
static __device__ __forceinline__ float bf16_to_f32(unsigned short h) {
  return __uint_as_float(((unsigned)h) << 16);
}

// ---- tiny deg-zero kernel (must complete before prep_csr's csr blocks) ----
#define ZERO_BLOCKS 782  // ceil(50000*16/4/256)
__global__ __launch_bounds__(256) void zero_deg_kernel(int* __restrict__ deg) {
  int i = (blockIdx.x * 256 + threadIdx.x) * 4;
  if (i < N_NODES * DEGSTRIDE) *(int4*)(deg + i) = make_int4(0, 0, 0, 0);
}

#define CSRB 1024         // csr blocks, FIRST in grid; co-resident so
                          // blockIdx&7 == XCD class (round-robin placement)
#define ECHUNKS 586       // ceil(600000/1024) edge chunks of 1024 edges
#define CONV_BLOCKS 6250  // (N*128/4)/256
#define W_BLOCKS 408      // (6*16384 + 48*128)/256

// == combined prep + XCD-partitioned CSR ====================================
// csr theory (R6): the 42us wall is cross-XCD line ping-pong — every deg/col
// line is RMW'd from all 8 XCDs (~12x per line) and partial dirty lines spill
// to HBM (WRITE_SIZE 48MB at ~1TB/s == the whole dispatch). Fix: XCD class
// k = blockIdx&7 scans the WHOLE edge list (8x scan = +38MB streaming, ~7us)
// but keeps only edges with dst in its 6250-node chunk -> each deg/col line
// is touched by ONE XCD: L2-local atomics, no coherence ping-pong, no
// partial-line writeback storm. Correct regardless of the real block->XCD
// mapping (filter is pure index arithmetic). Prep blocks follow and overlap.
__global__ __launch_bounds__(256) void prep_csr_kernel(
    const float* __restrict__ x, const float* __restrict__ W1,
    const float* __restrict__ W2, const float* __restrict__ Wc,
    const int* __restrict__ ei, unsigned short* __restrict__ xb,
    unsigned short* __restrict__ WT, unsigned short* __restrict__ WcT,
    unsigned short* __restrict__ hb1, int* __restrict__ deg,
    int* __restrict__ col) {
  const int b = blockIdx.x;
  const int t = threadIdx.x;
  if (b < CSRB) {
    const int lo = (b & 7) * CHUNK;
    const int hi = lo + CHUNK;
    for (int c = (b >> 3); c < ECHUNKS; c += (CSRB >> 3)) {
      int base = (c * 256 + t) * 4;
      if (base >= N_EDGES) continue;  // N_EDGES%4==0: all-or-none per int4
      int4 s4 = *(const int4*)(ei + base);
      int4 d4 = *(const int4*)(ei + N_EDGES + base);
      if (d4.x >= lo && d4.x < hi) {
        int p = atomicAdd(&deg[(size_t)d4.x * DEGSTRIDE], 1);
        col[(size_t)d4.x * DSTRIDE + p] = s4.x;
      }
      if (d4.y >= lo && d4.y < hi) {
        int p = atomicAdd(&deg[(size_t)d4.y * DEGSTRIDE], 1);
        col[(size_t)d4.y * DSTRIDE + p] = s4.y;
      }
      if (d4.z >= lo && d4.z < hi) {
        int p = atomicAdd(&deg[(size_t)d4.z * DEGSTRIDE], 1);
        col[(size_t)d4.z * DSTRIDE + p] = s4.z;
      }
      if (d4.w >= lo && d4.w < hi) {
        int p = atomicAdd(&deg[(size_t)d4.w * DEGSTRIDE], 1);
        col[(size_t)d4.w * DSTRIDE + p] = s4.w;
      }
    }
  } else if (b < CSRB + CONV_BLOCKS) {
    int i = ((b - CSRB) * 256 + t) * 4;
    if (i < N_NODES * 128) {
      float4 v = *(const float4*)(x + i);
      ushort4 o;
      o.x = f32_to_bf16(v.x); o.y = f32_to_bf16(v.y);
      o.z = f32_to_bf16(v.z); o.w = f32_to_bf16(v.w);
      *(ushort4*)(xb + i) = o;
    }
  } else if (b < CSRB + CONV_BLOCKS + W_BLOCKS) {
    int o = (b - CSRB - CONV_BLOCKS) * 256 + t;
    if (o < 6 * 16384) {
      int mat = o >> 14;
      int r = o & 16383;
      int n = r >> 7;
      int k = r & 127;
      const float* W = (mat < 3) ? (W1 + (size_t)mat * 16384)
                                 : (W2 + (size_t)(mat - 3) * 16384);
      WT[(size_t)mat * 16384 + (size_t)n * 128 + k] =
          f32_to_bf16(W[(size_t)k * 128 + n]);
    } else if (o < 6 * 16384 + 48 * 128) {
      int r = o - 6 * 16384;
      int n = r >> 7;
      int k = r & 127;
      float v = (n < OUT_CH) ? Wc[(size_t)k * OUT_CH + n] : 0.0f;
      WcT[(size_t)n * 128 + k] = f32_to_bf16(v);
    }
  } else {
    // zero phantom rows (index N_NODES) of the two gather sources
    if (t < 128) xb[(size_t)N_NODES * 128 + t] = 0;
    else hb1[(size_t)N_NODES * 128 + (t - 128)] = 0;
  }
}

// ================= Aggregation (bf16): z = h[n] + sum_nbrs ==================
// R1-exact form (v2's 2-row gather + shfl fold regressed: 18.5M LDS bank
// conflicts, VALU 9->23%). One 64-lane wave per node; lane owns 2 channels
// (64 lanes = one 256B row per gather); 16 row-gathers in flight; deg/col
// wave-uniform via readfirstlane; tail clamps to the phantom zero row.
// Node->block mapping uses the SAME XCD chunking as the csr build, so
// deg/col reads hit their home-XCD L2 (lines are dirty-resident there).
#define AGGR_GRID 12504  // 8 * 1563 (1563 blocks of 4 nodes per chunk)
__global__ __launch_bounds__(256) void aggregate_kernel(
    const unsigned short* __restrict__ h, const int* __restrict__ deg,
    const int* __restrict__ col, unsigned short* __restrict__ z) {
  const int xcd = blockIdx.x & 7;
  const int idx = blockIdx.x >> 3;
  int local = idx * 4 + (threadIdx.x >> 6);
  if (local >= CHUNK) return;
  int n = __builtin_amdgcn_readfirstlane(xcd * CHUNK + local);
  int q = threadIdx.x & 63;
  const size_t co = (size_t)q * 2;
  ushort2 sv = *(const ushort2*)(h + (size_t)n * 128 + co);
  float ax[8], ay[8];
#pragma unroll
  for (int k = 0; k < 8; ++k) { ax[k] = 0.f; ay[k] = 0.f; }
  ax[0] = bf16_to_f32(sv.x);
  ay[0] = bf16_to_f32(sv.y);
  int dg = __builtin_amdgcn_readfirstlane(deg[(size_t)n * DEGSTRIDE]);
  int cnt = (dg + 15) & ~15;
  const int* cp = col + (size_t)n * DSTRIDE;
  for (int i = 0; i < cnt; i += 16) {
    int ss[16];
#pragma unroll
    for (int k = 0; k < 16; ++k) {
      int sl = cp[i + k];  // in-bounds; garbage beyond dg is clamped below
      ss[k] = __builtin_amdgcn_readfirstlane((i + k < dg) ? sl : N_NODES);
    }
    ushort2 vv[16];
#pragma unroll
    for (int k = 0; k < 16; ++k)
      vv[k] = *(const ushort2*)(h + (size_t)ss[k] * 128 + co);
#pragma unroll
    for (int k = 0; k < 16; ++k) {
      ax[k & 7] += bf16_to_f32(vv[k].x);
      ay[k & 7] += bf16_to_f32(vv[k].y);
    }
  }
  float s0 = (ax[0] + ax[1]) + (ax[2] + ax[3]) + (ax[4] + ax[5]) + (ax[6] + ax[7]);
  float s1 = (ay[0] + ay[1]) + (ay[2] + ay[3]) + (ay[4] + ay[5]) + (ay[6] + ay[7]);
  ushort2 o;
  o.x = f32_to_bf16(s0);
  o.y = f32_to_bf16(s1);
  *(ushort2*)(z + (size_t)n * 128 + co) = o;
}

// ============ Fused layer MLP: Z = relu(relu(A@W1+b1)@W2+b2) ===============
// LDS-staged weights + 16 rows/wave. 64 rows/block, 4 waves. W staged into
// LDS once per GEMM (32KB, L2-hot source); B-frags become ds_read_b128.
// LDS = 34.8K (Wl) + 17.4K (T) = 52.2K -> 3 blocks/CU. Intermediate T rows
// wave-private; barriers only around Wl restage. LAST=true fuses the
// classifier (WcT direct-global; out f32).
// Frag layouts (measured m89/m91): A/B [idx=lane&15][k=(lane>>4)*8+j];
// C/D row=(lane>>4)*4+reg, col=lane&15.
template <bool LAST>
__global__ __launch_bounds__(256) void layer_pair_kernel(
    const unsigned short* __restrict__ A, const unsigned short* __restrict__ WT1,
    const float* __restrict__ b1, const unsigned short* __restrict__ WT2,
    const float* __restrict__ b2, unsigned short* __restrict__ Z,
    const unsigned short* __restrict__ WcT, const float* __restrict__ bc,
    float* __restrict__ out, int M) {
  __shared__ __align__(16) unsigned short Wl[128][136];  // staged weight
  __shared__ __align__(16) unsigned short T[64][136];    // activations
  const int tid = threadIdx.x;
  const int w = tid >> 6;
  const int lane = tid & 63;
  const int qg = lane >> 4;
  const int ln = lane & 15;
  const int row0 = blockIdx.x * 64;
  const int rbase = w * 16;
  const int r0 = row0 + rbase + ln;
  const short8 zero8 = {0, 0, 0, 0, 0, 0, 0, 0};

  // ---- stage WT1 -> Wl (2048 chunks of 8 bf16 over 256 threads) ----
#pragma unroll
  for (int j = 0; j < 8; ++j) {
    int slot = tid + j * 256;
    int row = slot >> 4;
    int kb = slot & 15;
    *(short8*)&Wl[row][kb * 8] = *(const short8*)(WT1 + (size_t)row * 128 + kb * 8);
  }
  __syncthreads();

  // ---- GEMM1: A direct-global, B from LDS ----
  floatx4 acc[8];
#pragma unroll
  for (int ct = 0; ct < 8; ++ct) acc[ct] = (floatx4){0.f, 0.f, 0.f, 0.f};
#pragma unroll
  for (int ks = 0; ks < 4; ++ks) {
    const int koff = ks * 32 + qg * 8;
    short8 a = (r0 < M) ? *(const short8*)(A + (size_t)r0 * 128 + koff) : zero8;
#pragma unroll
    for (int ct = 0; ct < 8; ++ct) {
      short8 b = *(const short8*)&Wl[ct * 16 + ln][koff];
      acc[ct] = __builtin_amdgcn_mfma_f32_16x16x32_bf16(a, b, acc[ct], 0, 0, 0);
    }
  }
  // ---- epilogue1 -> wave-private T rows (bias+relu+bf16) ----
#pragma unroll
  for (int ct = 0; ct < 8; ++ct) {
    float bv = b1[ct * 16 + ln];
#pragma unroll
    for (int r = 0; r < 4; ++r) {
      float v = fmaxf(acc[ct][r] + bv, 0.0f);
      T[rbase + qg * 4 + r][ct * 16 + ln] = f32_to_bf16(v);
    }
  }

  // ---- restage Wl with WT2 (all waves must be done with WT1) ----
  __syncthreads();
#pragma unroll
  for (int j = 0; j < 8; ++j) {
    int slot = tid + j * 256;
    int row = slot >> 4;
    int kb = slot & 15;
    *(short8*)&Wl[row][kb * 8] = *(const short8*)(WT2 + (size_t)row * 128 + kb * 8);
  }
  __syncthreads();

  // ---- GEMM2: A from own T rows, B from LDS ----
  floatx4 acc2[8];
#pragma unroll
  for (int ct = 0; ct < 8; ++ct) acc2[ct] = (floatx4){0.f, 0.f, 0.f, 0.f};
#pragma unroll
  for (int ks = 0; ks < 4; ++ks) {
    const int koff = ks * 32 + qg * 8;
    short8 a = *(const short8*)&T[rbase + ln][koff];
#pragma unroll
    for (int ct = 0; ct < 8; ++ct) {
      short8 b = *(const short8*)&Wl[ct * 16 + ln][koff];
      acc2[ct] = __builtin_amdgcn_mfma_f32_16x16x32_bf16(a, b, acc2[ct], 0, 0, 0);
    }
  }
  // ---- epilogue2 -> own T rows ----
#pragma unroll
  for (int ct = 0; ct < 8; ++ct) {
    float bv = b2[ct * 16 + ln];
#pragma unroll
    for (int r = 0; r < 4; ++r) {
      float v = fmaxf(acc2[ct][r] + bv, 0.0f);
      T[rbase + qg * 4 + r][ct * 16 + ln] = f32_to_bf16(v);
    }
  }

  if (LAST) {
    // ---- GEMM3 (classifier): A from own T rows, B = WcT direct-global ----
    floatx4 acc3[3];
#pragma unroll
    for (int ct = 0; ct < 3; ++ct) acc3[ct] = (floatx4){0.f, 0.f, 0.f, 0.f};
#pragma unroll
    for (int ks = 0; ks < 4; ++ks) {
      const int koff = ks * 32 + qg * 8;
      short8 a = *(const short8*)&T[rbase + ln][koff];
#pragma unroll
      for (int ct = 0; ct < 3; ++ct) {
        short8 b = *(const short8*)(WcT + (size_t)(ct * 16 + ln) * 128 + koff);
        acc3[ct] = __builtin_amdgcn_mfma_f32_16x16x32_bf16(a, b, acc3[ct], 0, 0, 0);
      }
    }
#pragma unroll
    for (int ct = 0; ct < 3; ++ct) {
      int colg = ct * 16 + ln;
      if (colg < OUT_CH) {
        float bv = bc[colg];
#pragma unroll
        for (int r = 0; r < 4; ++r) {
          int row = row0 + rbase + qg * 4 + r;
          if (row < M) out[(size_t)row * OUT_CH + colg] = acc3[ct][r] + bv;
        }
      }
    }
  } else {
    __syncthreads();
    // ---- cooperative coalesced store: 64 rows x 256B ----
#pragma unroll
    for (int j = 0; j < 4; ++j) {
      int slot = tid + j * 256;  // 0..1023 chunks of 8 bf16
      int row = slot >> 4;
      int kb = slot & 15;
      if (row0 + row < M) {
        short8 v = *(const short8*)&T[row][kb * 8];
        *(short8*)(Z + (size_t)(row0 + row) * 128 + kb * 8) = v;
      }
    }
  }
}

// ---------------------------------------------------------------------------
extern "C" void kernel_launch(void* const* d_in, const int* in_sizes, int n_in,
                              void* d_out, int out_size, void* d_ws,
                              size_t ws_size, hipStream_t stream) {
  const float* x = (const float*)d_in[0];
  const int* ei = (const int*)d_in[2];  // int32 [2, E]
  const float* W1 = (const float*)d_in[3];
  const float* b1 = (const float*)d_in[4];
  const float* W2 = (const float*)d_in[5];
  const float* b2 = (const float*)d_in[6];
  const float* Wc = (const float*)d_in[7];
  const float* bc = (const float*)d_in[8];
  float* out = (float*)d_out;

  // Node buffers have N+1 rows: row N_NODES is the phantom zero row.
  const size_t NF = (size_t)(N_NODES + 1) * 128;
  unsigned short* hb0 = (unsigned short*)d_ws;
  unsigned short* hb1 = hb0 + NF;
  unsigned short* xbf = hb1 + NF;
  unsigned short* WT = xbf + NF;         // 6*16384 bf16
  unsigned short* WcT = WT + 6 * 16384;  // 48*128 bf16
  int* deg = (int*)(WcT + 48 * 128);     // [N * DEGSTRIDE] (64B-padded ctrs)
  int* col = deg + (size_t)N_NODES * DEGSTRIDE;  // [N * DSTRIDE]

  const dim3 blk(256);
  const int pair_grid = (N_NODES + 63) / 64;  // 782

  // ---- deg = 0 (tiny; must complete before prep_csr's csr blocks) ----
  zero_deg_kernel<<<ZERO_BLOCKS, blk, 0, stream>>>(deg);

  // ---- combined prep + XCD-partitioned CSR ----
  prep_csr_kernel<<<CSRB + CONV_BLOCKS + W_BLOCKS + 1, blk, 0, stream>>>(
      x, W1, W2, Wc, ei, xbf, WT, WcT, hb1, deg, col);

  // ---- 3 GIN layers; classifier fused into the last pair ----
  // Fixed buffers: agg h->hb0; pair hb0->hb1; next h = hb1 (old h dead).
  const unsigned short* h = xbf;
  for (int l = 0; l < N_LAYERS; ++l) {
    aggregate_kernel<<<AGGR_GRID, blk, 0, stream>>>(h, deg, col, hb0);
    if (l < N_LAYERS - 1) {
      layer_pair_kernel<false><<<pair_grid, blk, 0, stream>>>(
          hb0, WT + (size_t)l * 16384, b1 + (size_t)l * 128,
          WT + (size_t)(3 + l) * 16384, b2 + (size_t)l * 128, hb1,
          nullptr, nullptr, nullptr, N_NODES);
      h = hb1;
    } else {
      layer_pair_kernel<true><<<pair_grid, blk, 0, stream>>>(
          hb0, WT + (size_t)l * 16384, b1 + (size_t)l * 128,
          WT + (size_t)(3 + l) * 16384, b2 + (size_t)l * 128, nullptr,
          WcT, bc, out, N_NODES);
    }
  }
}

// Round 8
// 237.234 us; speedup vs baseline: 1.4146x; 1.0030x over previous
//
#include <hip/hip_runtime.h>

#define N_NODES 50000
#define IN_CH 128
#define HID 128
#define OUT_CH 40
#define N_LAYERS 3
#define N_EDGES 600000
#define DSTRIDE 64    // fixed col slots/node; P(Poisson(12) > 64) ~ 1e-30
#define DEGSTRIDE 16  // 64B per counter
#define NXCD 8
#define CHUNK 6250    // nodes per XCD class (N/8)

typedef __attribute__((ext_vector_type(8))) short short8;
typedef __attribute__((ext_vector_type(4))) float floatx4;

static __device__ __forceinline__ unsigned short f32_to_bf16(float f) {
  unsigned u = __float_as_uint(f);
  unsigned r = 0x7FFFu + ((u >> 16) & 1u);  // RNE
  return (unsigned short)((u + r) >> 16);
}
static __device__ __forceinline__ float bf16_to_f32(unsigned short h) {
  return __uint_as_float(((unsigned)h) << 16);
}

// ---- tiny deg-zero kernel (must complete before prep_csr's csr blocks) ----
#define ZERO_BLOCKS 782  // ceil(50000*16/4/256)
__global__ __launch_bounds__(256) void zero_deg_kernel(int* __restrict__ deg) {
  int i = (blockIdx.x * 256 + threadIdx.x) * 4;
  if (i < N_NODES * DEGSTRIDE) *(int4*)(deg + i) = make_int4(0, 0, 0, 0);
}

#define CSRB 1024         // csr blocks, FIRST in grid; co-resident so
                          // blockIdx&7 == XCD class (round-robin placement)
#define ECHUNKS 586       // ceil(600000/1024) edge chunks of 1024 edges
#define CONV_BLOCKS 6250  // (N*128/4)/256
#define W_BLOCKS 408      // (6*16384 + 48*128)/256

// == combined prep + XCD-partitioned CSR ====================================
// Verified R7: XCD class k = blockIdx&7 keeps only edges with dst in its
// 6250-node chunk -> each deg/col line is RMW'd by ONE XCD: L2-local
// atomics, no cross-XCD ping-pong, no partial-line writeback storm.
// prep_csr dropped below the 41.7us fill threshold (was 45.2 unpartitioned).
__global__ __launch_bounds__(256) void prep_csr_kernel(
    const float* __restrict__ x, const float* __restrict__ W1,
    const float* __restrict__ W2, const float* __restrict__ Wc,
    const int* __restrict__ ei, unsigned short* __restrict__ xb,
    unsigned short* __restrict__ WT, unsigned short* __restrict__ WcT,
    unsigned short* __restrict__ hb1, int* __restrict__ deg,
    int* __restrict__ col) {
  const int b = blockIdx.x;
  const int t = threadIdx.x;
  if (b < CSRB) {
    const int lo = (b & 7) * CHUNK;
    const int hi = lo + CHUNK;
    for (int c = (b >> 3); c < ECHUNKS; c += (CSRB >> 3)) {
      int base = (c * 256 + t) * 4;
      if (base >= N_EDGES) continue;  // N_EDGES%4==0: all-or-none per int4
      int4 s4 = *(const int4*)(ei + base);
      int4 d4 = *(const int4*)(ei + N_EDGES + base);
      if (d4.x >= lo && d4.x < hi) {
        int p = atomicAdd(&deg[(size_t)d4.x * DEGSTRIDE], 1);
        col[(size_t)d4.x * DSTRIDE + p] = s4.x;
      }
      if (d4.y >= lo && d4.y < hi) {
        int p = atomicAdd(&deg[(size_t)d4.y * DEGSTRIDE], 1);
        col[(size_t)d4.y * DSTRIDE + p] = s4.y;
      }
      if (d4.z >= lo && d4.z < hi) {
        int p = atomicAdd(&deg[(size_t)d4.z * DEGSTRIDE], 1);
        col[(size_t)d4.z * DSTRIDE + p] = s4.z;
      }
      if (d4.w >= lo && d4.w < hi) {
        int p = atomicAdd(&deg[(size_t)d4.w * DEGSTRIDE], 1);
        col[(size_t)d4.w * DSTRIDE + p] = s4.w;
      }
    }
  } else if (b < CSRB + CONV_BLOCKS) {
    int i = ((b - CSRB) * 256 + t) * 4;
    if (i < N_NODES * 128) {
      float4 v = *(const float4*)(x + i);
      ushort4 o;
      o.x = f32_to_bf16(v.x); o.y = f32_to_bf16(v.y);
      o.z = f32_to_bf16(v.z); o.w = f32_to_bf16(v.w);
      *(ushort4*)(xb + i) = o;
    }
  } else if (b < CSRB + CONV_BLOCKS + W_BLOCKS) {
    int o = (b - CSRB - CONV_BLOCKS) * 256 + t;
    if (o < 6 * 16384) {
      int mat = o >> 14;
      int r = o & 16383;
      int n = r >> 7;
      int k = r & 127;
      const float* W = (mat < 3) ? (W1 + (size_t)mat * 16384)
                                 : (W2 + (size_t)(mat - 3) * 16384);
      WT[(size_t)mat * 16384 + (size_t)n * 128 + k] =
          f32_to_bf16(W[(size_t)k * 128 + n]);
    } else if (o < 6 * 16384 + 48 * 128) {
      int r = o - 6 * 16384;
      int n = r >> 7;
      int k = r & 127;
      float v = (n < OUT_CH) ? Wc[(size_t)k * OUT_CH + n] : 0.0f;
      WcT[(size_t)n * 128 + k] = f32_to_bf16(v);
    }
  } else {
    // zero phantom rows (index N_NODES) of the two gather sources
    if (t < 128) xb[(size_t)N_NODES * 128 + t] = 0;
    else hb1[(size_t)N_NODES * 128 + (t - 128)] = 0;
  }
}

// ================= Aggregation (bf16): z = h[n] + sum_nbrs ==================
// v3: TWO NODES PER WAVE, R1-exact per-node lane geometry (lane owns 2
// channels; one 256B row per gather; NO cross-lane ops — R2/R6's failure
// mode). Rationale: avg deg 12 caps in-flight gathers per node at ~16; a
// 1-node wave stalls on waitcnt after ~12 real requests. Interleaving 2
// nodes doubles independent requests per wave (32 in flight) before the
// first dependent use. Accum trimmed to 4 chains/channel to stay near the
// 64-VGPR occupancy cliff. Node->block mapping keeps the csr XCD chunking
// so deg/col reads hit their home-XCD L2.
#define AGGR_GRID 6256  // 8 * 782 (782 blocks of 8 nodes per chunk)
__global__ __launch_bounds__(256) void aggregate_kernel(
    const unsigned short* __restrict__ h, const int* __restrict__ deg,
    const int* __restrict__ col, unsigned short* __restrict__ z) {
  const int xcd = blockIdx.x & 7;
  const int idx = blockIdx.x >> 3;
  int local = idx * 8 + (threadIdx.x >> 6) * 2;  // 2 consecutive nodes/wave
  if (local >= CHUNK) return;  // CHUNK even -> n0,n1 both valid when taken
  int n0 = __builtin_amdgcn_readfirstlane(xcd * CHUNK + local);
  int n1 = n0 + 1;
  int q = threadIdx.x & 63;
  const size_t co = (size_t)q * 2;
  ushort2 sv0 = *(const ushort2*)(h + (size_t)n0 * 128 + co);
  ushort2 sv1 = *(const ushort2*)(h + (size_t)n1 * 128 + co);
  float ax0[4], ay0[4], ax1[4], ay1[4];
#pragma unroll
  for (int k = 0; k < 4; ++k) { ax0[k] = 0.f; ay0[k] = 0.f; ax1[k] = 0.f; ay1[k] = 0.f; }
  ax0[0] = bf16_to_f32(sv0.x);
  ay0[0] = bf16_to_f32(sv0.y);
  ax1[0] = bf16_to_f32(sv1.x);
  ay1[0] = bf16_to_f32(sv1.y);
  int dg0 = __builtin_amdgcn_readfirstlane(deg[(size_t)n0 * DEGSTRIDE]);
  int dg1 = __builtin_amdgcn_readfirstlane(deg[(size_t)n1 * DEGSTRIDE]);
  int cnt = ((dg0 > dg1 ? dg0 : dg1) + 15) & ~15;
  const int* cp0 = col + (size_t)n0 * DSTRIDE;
  const int* cp1 = col + (size_t)n1 * DSTRIDE;
  for (int i = 0; i < cnt; i += 16) {
    int ss0[16], ss1[16];
#pragma unroll
    for (int k = 0; k < 16; ++k) {
      int sl0 = cp0[i + k];  // in-bounds; garbage beyond dg clamped below
      int sl1 = cp1[i + k];
      ss0[k] = __builtin_amdgcn_readfirstlane((i + k < dg0) ? sl0 : N_NODES);
      ss1[k] = __builtin_amdgcn_readfirstlane((i + k < dg1) ? sl1 : N_NODES);
    }
    ushort2 v0[16], v1[16];
#pragma unroll
    for (int k = 0; k < 16; ++k) {
      v0[k] = *(const ushort2*)(h + (size_t)ss0[k] * 128 + co);
      v1[k] = *(const ushort2*)(h + (size_t)ss1[k] * 128 + co);
    }
#pragma unroll
    for (int k = 0; k < 16; ++k) {
      ax0[k & 3] += bf16_to_f32(v0[k].x);
      ay0[k & 3] += bf16_to_f32(v0[k].y);
      ax1[k & 3] += bf16_to_f32(v1[k].x);
      ay1[k & 3] += bf16_to_f32(v1[k].y);
    }
  }
  float s0x = (ax0[0] + ax0[1]) + (ax0[2] + ax0[3]);
  float s0y = (ay0[0] + ay0[1]) + (ay0[2] + ay0[3]);
  float s1x = (ax1[0] + ax1[1]) + (ax1[2] + ax1[3]);
  float s1y = (ay1[0] + ay1[1]) + (ay1[2] + ay1[3]);
  ushort2 o0, o1;
  o0.x = f32_to_bf16(s0x);
  o0.y = f32_to_bf16(s0y);
  o1.x = f32_to_bf16(s1x);
  o1.y = f32_to_bf16(s1y);
  *(ushort2*)(z + (size_t)n0 * 128 + co) = o0;
  *(ushort2*)(z + (size_t)n1 * 128 + co) = o1;
}

// ============ Fused layer MLP: Z = relu(relu(A@W1+b1)@W2+b2) ===============
// LDS-staged weights + 16 rows/wave. 64 rows/block, 4 waves. W staged into
// LDS once per GEMM (32KB, L2-hot source); B-frags become ds_read_b128.
// LDS = 34.8K (Wl) + 17.4K (T) = 52.2K -> 3 blocks/CU. Intermediate T rows
// wave-private; barriers only around Wl restage. LAST=true fuses the
// classifier (WcT direct-global; out f32).
// Frag layouts (measured m89/m91): A/B [idx=lane&15][k=(lane>>4)*8+j];
// C/D row=(lane>>4)*4+reg, col=lane&15.
template <bool LAST>
__global__ __launch_bounds__(256) void layer_pair_kernel(
    const unsigned short* __restrict__ A, const unsigned short* __restrict__ WT1,
    const float* __restrict__ b1, const unsigned short* __restrict__ WT2,
    const float* __restrict__ b2, unsigned short* __restrict__ Z,
    const unsigned short* __restrict__ WcT, const float* __restrict__ bc,
    float* __restrict__ out, int M) {
  __shared__ __align__(16) unsigned short Wl[128][136];  // staged weight
  __shared__ __align__(16) unsigned short T[64][136];    // activations
  const int tid = threadIdx.x;
  const int w = tid >> 6;
  const int lane = tid & 63;
  const int qg = lane >> 4;
  const int ln = lane & 15;
  const int row0 = blockIdx.x * 64;
  const int rbase = w * 16;
  const int r0 = row0 + rbase + ln;
  const short8 zero8 = {0, 0, 0, 0, 0, 0, 0, 0};

  // ---- stage WT1 -> Wl (2048 chunks of 8 bf16 over 256 threads) ----
#pragma unroll
  for (int j = 0; j < 8; ++j) {
    int slot = tid + j * 256;
    int row = slot >> 4;
    int kb = slot & 15;
    *(short8*)&Wl[row][kb * 8] = *(const short8*)(WT1 + (size_t)row * 128 + kb * 8);
  }
  __syncthreads();

  // ---- GEMM1: A direct-global, B from LDS ----
  floatx4 acc[8];
#pragma unroll
  for (int ct = 0; ct < 8; ++ct) acc[ct] = (floatx4){0.f, 0.f, 0.f, 0.f};
#pragma unroll
  for (int ks = 0; ks < 4; ++ks) {
    const int koff = ks * 32 + qg * 8;
    short8 a = (r0 < M) ? *(const short8*)(A + (size_t)r0 * 128 + koff) : zero8;
#pragma unroll
    for (int ct = 0; ct < 8; ++ct) {
      short8 b = *(const short8*)&Wl[ct * 16 + ln][koff];
      acc[ct] = __builtin_amdgcn_mfma_f32_16x16x32_bf16(a, b, acc[ct], 0, 0, 0);
    }
  }
  // ---- epilogue1 -> wave-private T rows (bias+relu+bf16) ----
#pragma unroll
  for (int ct = 0; ct < 8; ++ct) {
    float bv = b1[ct * 16 + ln];
#pragma unroll
    for (int r = 0; r < 4; ++r) {
      float v = fmaxf(acc[ct][r] + bv, 0.0f);
      T[rbase + qg * 4 + r][ct * 16 + ln] = f32_to_bf16(v);
    }
  }

  // ---- restage Wl with WT2 (all waves must be done with WT1) ----
  __syncthreads();
#pragma unroll
  for (int j = 0; j < 8; ++j) {
    int slot = tid + j * 256;
    int row = slot >> 4;
    int kb = slot & 15;
    *(short8*)&Wl[row][kb * 8] = *(const short8*)(WT2 + (size_t)row * 128 + kb * 8);
  }
  __syncthreads();

  // ---- GEMM2: A from own T rows, B from LDS ----
  floatx4 acc2[8];
#pragma unroll
  for (int ct = 0; ct < 8; ++ct) acc2[ct] = (floatx4){0.f, 0.f, 0.f, 0.f};
#pragma unroll
  for (int ks = 0; ks < 4; ++ks) {
    const int koff = ks * 32 + qg * 8;
    short8 a = *(const short8*)&T[rbase + ln][koff];
#pragma unroll
    for (int ct = 0; ct < 8; ++ct) {
      short8 b = *(const short8*)&Wl[ct * 16 + ln][koff];
      acc2[ct] = __builtin_amdgcn_mfma_f32_16x16x32_bf16(a, b, acc2[ct], 0, 0, 0);
    }
  }
  // ---- epilogue2 -> own T rows ----
#pragma unroll
  for (int ct = 0; ct < 8; ++ct) {
    float bv = b2[ct * 16 + ln];
#pragma unroll
    for (int r = 0; r < 4; ++r) {
      float v = fmaxf(acc2[ct][r] + bv, 0.0f);
      T[rbase + qg * 4 + r][ct * 16 + ln] = f32_to_bf16(v);
    }
  }

  if (LAST) {
    // ---- GEMM3 (classifier): A from own T rows, B = WcT direct-global ----
    floatx4 acc3[3];
#pragma unroll
    for (int ct = 0; ct < 3; ++ct) acc3[ct] = (floatx4){0.f, 0.f, 0.f, 0.f};
#pragma unroll
    for (int ks = 0; ks < 4; ++ks) {
      const int koff = ks * 32 + qg * 8;
      short8 a = *(const short8*)&T[rbase + ln][koff];
#pragma unroll
      for (int ct = 0; ct < 3; ++ct) {
        short8 b = *(const short8*)(WcT + (size_t)(ct * 16 + ln) * 128 + koff);
        acc3[ct] = __builtin_amdgcn_mfma_f32_16x16x32_bf16(a, b, acc3[ct], 0, 0, 0);
      }
    }
#pragma unroll
    for (int ct = 0; ct < 3; ++ct) {
      int colg = ct * 16 + ln;
      if (colg < OUT_CH) {
        float bv = bc[colg];
#pragma unroll
        for (int r = 0; r < 4; ++r) {
          int row = row0 + rbase + qg * 4 + r;
          if (row < M) out[(size_t)row * OUT_CH + colg] = acc3[ct][r] + bv;
        }
      }
    }
  } else {
    __syncthreads();
    // ---- cooperative coalesced store: 64 rows x 256B ----
#pragma unroll
    for (int j = 0; j < 4; ++j) {
      int slot = tid + j * 256;  // 0..1023 chunks of 8 bf16
      int row = slot >> 4;
      int kb = slot & 15;
      if (row0 + row < M) {
        short8 v = *(const short8*)&T[row][kb * 8];
        *(short8*)(Z + (size_t)(row0 + row) * 128 + kb * 8) = v;
      }
    }
  }
}

// ---------------------------------------------------------------------------
extern "C" void kernel_launch(void* const* d_in, const int* in_sizes, int n_in,
                              void* d_out, int out_size, void* d_ws,
                              size_t ws_size, hipStream_t stream) {
  const float* x = (const float*)d_in[0];
  const int* ei = (const int*)d_in[2];  // int32 [2, E]
  const float* W1 = (const float*)d_in[3];
  const float* b1 = (const float*)d_in[4];
  const float* W2 = (const float*)d_in[5];
  const float* b2 = (const float*)d_in[6];
  const float* Wc = (const float*)d_in[7];
  const float* bc = (const float*)d_in[8];
  float* out = (float*)d_out;

  // Node buffers have N+1 rows: row N_NODES is the phantom zero row.
  const size_t NF = (size_t)(N_NODES + 1) * 128;
  unsigned short* hb0 = (unsigned short*)d_ws;
  unsigned short* hb1 = hb0 + NF;
  unsigned short* xbf = hb1 + NF;
  unsigned short* WT = xbf + NF;         // 6*16384 bf16
  unsigned short* WcT = WT + 6 * 16384;  // 48*128 bf16
  int* deg = (int*)(WcT + 48 * 128);     // [N * DEGSTRIDE] (64B-padded ctrs)
  int* col = deg + (size_t)N_NODES * DEGSTRIDE;  // [N * DSTRIDE]

  const dim3 blk(256);
  const int pair_grid = (N_NODES + 63) / 64;  // 782

  // ---- deg = 0 (tiny; must complete before prep_csr's csr blocks) ----
  zero_deg_kernel<<<ZERO_BLOCKS, blk, 0, stream>>>(deg);

  // ---- combined prep + XCD-partitioned CSR ----
  prep_csr_kernel<<<CSRB + CONV_BLOCKS + W_BLOCKS + 1, blk, 0, stream>>>(
      x, W1, W2, Wc, ei, xbf, WT, WcT, hb1, deg, col);

  // ---- 3 GIN layers; classifier fused into the last pair ----
  // Fixed buffers: agg h->hb0; pair hb0->hb1; next h = hb1 (old h dead).
  const unsigned short* h = xbf;
  for (int l = 0; l < N_LAYERS; ++l) {
    aggregate_kernel<<<AGGR_GRID, blk, 0, stream>>>(h, deg, col, hb0);
    if (l < N_LAYERS - 1) {
      layer_pair_kernel<false><<<pair_grid, blk, 0, stream>>>(
          hb0, WT + (size_t)l * 16384, b1 + (size_t)l * 128,
          WT + (size_t)(3 + l) * 16384, b2 + (size_t)l * 128, hb1,
          nullptr, nullptr, nullptr, N_NODES);
      h = hb1;
    } else {
      layer_pair_kernel<true><<<pair_grid, blk, 0, stream>>>(
          hb0, WT + (size_t)l * 16384, b1 + (size_t)l * 128,
          WT + (size_t)(3 + l) * 16384, b2 + (size_t)l * 128, nullptr,
          WcT, bc, out, N_NODES);
    }
  }
}